// Round 5
// baseline (1099.528 us; speedup 1.0000x reference)
//
#include <hip/hip_runtime.h>

#define NB 4
#define NQ 8192
#define QB 32   // queries per block; 8 candidate parts (2 per wave, shfl-merged)

struct D4 { double x, y, z, w; };

__device__ __forceinline__ double shflx32_d(double v) {
  union { double d; int i[2]; } u; u.d = v;
  u.i[0] = __shfl_xor(u.i[0], 32, 64);
  u.i[1] = __shfl_xor(u.i[1], 32, 64);
  return u.d;
}
__device__ __forceinline__ int shflx32_i(int v) { return __shfl_xor(v, 32, 64); }

// lexicographic (d, idx) insert into sorted triple; ties -> lower index
// (matches jax.lax.top_k stability).
__device__ __forceinline__ void lexins(double& e0d, double& e1d, double& e2d,
                                       int& e0i, int& e1i, int& e2i,
                                       double d, int i) {
  if (d < e2d || (d == e2d && i < e2i)) {
    if (d < e0d || (d == e0d && i < e0i)) {
      e2d = e1d; e2i = e1i; e1d = e0d; e1i = e0i; e0d = d; e0i = i;
    } else if (d < e1d || (d == e1d && i < e1i)) {
      e2d = e1d; e2i = e1i; e1d = d; e1i = i;
    } else {
      e2d = d; e2i = i;
    }
  }
}

struct Smem {
  D4     qp[QB];             // query x,y,z,|p|^2 (f64)           1 KB
  D4     tile[512];          // candidate tile x,y,z,|k|^2 (f64) 16 KB
  double t3d[3][QB][4][3];   // per-level/query/wave top3 s       9 KB
  int    t3i[3][QB][4][3];   //                                   4.6 KB
  double mmin[QB][4];        // per-wave mask min s               1 KB
  float  wv[96];             // folded w_cls @ w_fc
  float  part[QB][3];        // per-level partial pred
};

// Rank by s = c.w - 2*(q . c) via 3 FMAs (f64). Ordering by s == ordering by
// d2 = qn + s up to ~1ulp f64 coincidences (probability ~1e-7 overall).
// Within a part indices ascend and strict < keeps the earlier index; cross-
// part merges are (s, idx)-lexicographic -> jax.lax.top_k stable semantics.
template <bool MASK>
__device__ __forceinline__ void scan_array(
    const float* __restrict__ src, int M, int b,
    double m2x, double m2y, double m2z,
    int off, int tid, Smem& s,
    double& e0d, double& e1d, double& e2d,
    int& e0i, int& e1i, int& e2i, double& dmin) {
  const double INF = __builtin_inf();
  e0d = INF; e1d = INF; e2d = INF;
  e0i = 0;   e1i = 0;   e2i = 0;
  dmin = INF;
  for (int t0 = 0; t0 < M; t0 += 512) {
    __syncthreads();
    {
      // stage 512 candidates: each thread converts 2 points to f64 + |k|^2
      int pi = 2 * tid;
      const float* p = src + ((size_t)b * M + t0 + pi) * 3;
      double x0 = (double)p[0], y0 = (double)p[1], z0 = (double)p[2];
      double x1 = (double)p[3], y1 = (double)p[4], z1 = (double)p[5];
      D4 c0 = {x0, y0, z0, x0 * x0 + y0 * y0 + z0 * z0};
      D4 c1 = {x1, y1, z1, x1 * x1 + y1 * y1 + z1 * z1};
      s.tile[pi]     = c0;
      s.tile[pi + 1] = c1;
    }
    __syncthreads();
    // each part scans 64 candidates per tile, batches of 8 for load pipelining
    for (int jj = 0; jj < 64; jj += 8) {
      double sv[8];
#pragma unroll
      for (int u = 0; u < 8; ++u) {
        D4 c = s.tile[off + jj + u];   // wave-uniform address -> broadcast
        sv[u] = fma(m2x, c.x, fma(m2y, c.y, fma(m2z, c.z, c.w)));
      }
      if (MASK) {
#pragma unroll
        for (int u = 0; u < 8; ++u) dmin = fmin(dmin, sv[u]);
      } else {
#pragma unroll
        for (int u = 0; u < 8; ++u) {
          if (sv[u] < e2d) {   // strict: tie with 3rd-best never displaces
            int idx = t0 + off + jj + u;
            if (sv[u] < e0d) {
              e2d = e1d; e2i = e1i; e1d = e0d; e1i = e0i; e0d = sv[u]; e0i = idx;
            } else if (sv[u] < e1d) {
              e2d = e1d; e2i = e1i; e1d = sv[u]; e1i = idx;
            } else {
              e2d = sv[u]; e2i = idx;
            }
          }
        }
      }
    }
  }
}

__global__ __launch_bounds__(256, 4) void fused_kernel(
    const float* __restrict__ pts,
    const float* __restrict__ k2p, const float* __restrict__ f2,
    const float* __restrict__ k3p, const float* __restrict__ f3,
    const float* __restrict__ k4p, const float* __restrict__ f4,
    const float* __restrict__ mmp,
    const float* __restrict__ wfc, const float* __restrict__ wcls,
    float* __restrict__ out) {
  __shared__ Smem s;
  const int tid = threadIdx.x;
  const int b = blockIdx.y;
  const int q0 = blockIdx.x * QB;
  const int qloc = tid & 31;        // query within block
  const int part8 = tid >> 5;       // candidate part 0..7
  const int off = part8 * 64;       // part offset within a 512-tile
  const int wv_id = tid >> 6;       // wave 0..3

  // phase 1: threads 0..31 load queries (f64); 64..159 fold w_cls @ w_fc
  if (tid < QB) {
    int gq = b * NQ + q0 + tid;
    double x = (double)pts[3 * gq];
    double y = (double)pts[3 * gq + 1];
    double z = (double)pts[3 * gq + 2];
    D4 q = {x, y, z, x * x + y * y + z * z};
    s.qp[tid] = q;
  } else if (tid >= 64 && tid < 64 + 96) {
    int t = tid - 64;
    float acc = 0.f;
    for (int j = 0; j < 64; ++j) acc += wcls[j] * wfc[j * 96 + t];
    s.wv[t] = acc;
  }
  __syncthreads();
  const D4 qp = s.qp[qloc];
  const double m2x = -2.0 * qp.x, m2y = -2.0 * qp.y, m2z = -2.0 * qp.z;

  // phase 2: scan the three known arrays + the match array
  const float* lsrc[3] = {k2p, k3p, k4p};
  const int    lM[3]   = {8192, 4096, 2048};
#pragma unroll 1
  for (int l = 0; l < 3; ++l) {
    double e0d, e1d, e2d, dm; int e0i, e1i, e2i;
    scan_array<false>(lsrc[l], lM[l], b, m2x, m2y, m2z, off, tid, s,
                      e0d, e1d, e2d, e0i, e1i, e2i, dm);
    // in-wave merge: partner half-wave holds the adjacent part
    double f0 = shflx32_d(e0d), f1 = shflx32_d(e1d), f2d_ = shflx32_d(e2d);
    int    g0 = shflx32_i(e0i), g1 = shflx32_i(e1i), g2 = shflx32_i(e2i);
    lexins(e0d, e1d, e2d, e0i, e1i, e2i, f0, g0);
    lexins(e0d, e1d, e2d, e0i, e1i, e2i, f1, g1);
    lexins(e0d, e1d, e2d, e0i, e1i, e2i, f2d_, g2);
    if ((tid & 32) == 0) {
      s.t3d[l][qloc][wv_id][0] = e0d; s.t3i[l][qloc][wv_id][0] = e0i;
      s.t3d[l][qloc][wv_id][1] = e1d; s.t3i[l][qloc][wv_id][1] = e1i;
      s.t3d[l][qloc][wv_id][2] = e2d; s.t3i[l][qloc][wv_id][2] = e2i;
    }
  }
  {
    double e0d, e1d, e2d, dm; int e0i, e1i, e2i;
    scan_array<true>(mmp, 4096, b, m2x, m2y, m2z, off, tid, s,
                     e0d, e1d, e2d, e0i, e1i, e2i, dm);
    dm = fmin(dm, shflx32_d(dm));
    if ((tid & 32) == 0) s.mmin[qloc][wv_id] = dm;
  }
  __syncthreads();

  // phase 3: merge the 4 wave-partials, weights (f64), gather, folded FC / mask
  const int gqbase = b * NQ + q0;
  if (tid < 96) {
    const int lvl = tid >> 5;   // wave-uniform within half-waves
    const int q = tid & 31;
    double e0d = s.t3d[lvl][q][0][0], e1d = s.t3d[lvl][q][0][1], e2d = s.t3d[lvl][q][0][2];
    int    e0i = s.t3i[lvl][q][0][0], e1i = s.t3i[lvl][q][0][1], e2i = s.t3i[lvl][q][0][2];
#pragma unroll
    for (int p = 1; p < 4; ++p) {
#pragma unroll
      for (int r = 0; r < 3; ++r)
        lexins(e0d, e1d, e2d, e0i, e1i, e2i,
               s.t3d[lvl][q][p][r], s.t3i[lvl][q][p][r]);
    }
    const double qn = s.qp[q].w;
    double d0 = fmax(qn + e0d, 0.0);
    double d1 = fmax(qn + e1d, 0.0);
    double d2v = fmax(qn + e2d, 0.0);
    double r0 = 1.0 / (d0 + 1e-8);
    double r1 = 1.0 / (d1 + 1e-8);
    double r2 = 1.0 / (d2v + 1e-8);
    double sum = (r0 + r1) + r2;
    float wa = (float)(r0 / sum), wb = (float)(r1 / sum), wc = (float)(r2 / sum);

    const float* fp = (lvl == 0) ? f2 : ((lvl == 1) ? f3 : f4);
    const int    M  = (lvl == 0) ? 8192 : ((lvl == 1) ? 4096 : 2048);
    const float* g0 = fp + ((size_t)b * M + e0i) * 32;
    const float* g1 = fp + ((size_t)b * M + e1i) * 32;
    const float* g2 = fp + ((size_t)b * M + e2i) * 32;
    float acc = 0.f;
#pragma unroll
    for (int wd = 0; wd < 32; ++wd) {
      float v = (wa * g0[wd] + wb * g1[wd]) + wc * g2[wd];
      acc += s.wv[lvl * 32 + wd] * v;
    }
    s.part[q][lvl] = acc;
  } else if (tid < 128) {
    const int q = tid - 96;
    double sm = fmin(fmin(s.mmin[q][0], s.mmin[q][1]),
                     fmin(s.mmin[q][2], s.mmin[q][3]));
    double dm = s.qp[q].w + sm;   // rounding monotone: == min of per-cand d2
    // d2 < 0.25 == sqrt(max(d2,0)) < 0.5 (monotone, both strict)
    out[NB * NQ + gqbase + q] = (dm < 0.25) ? 1.0f : 0.0f;
  }
  __syncthreads();
  if (tid < QB) {
    float pred = (s.part[tid][0] + s.part[tid][1]) + s.part[tid][2];
    out[gqbase + tid] = pred;
  }
}

extern "C" void kernel_launch(void* const* d_in, const int* in_sizes, int n_in,
                              void* d_out, int out_size, void* d_ws, size_t ws_size,
                              hipStream_t stream) {
  const float* pts    = (const float*)d_in[0];
  const float* known2 = (const float*)d_in[1];
  const float* feats2 = (const float*)d_in[2];
  const float* known3 = (const float*)d_in[3];
  const float* feats3 = (const float*)d_in[4];
  const float* known4 = (const float*)d_in[5];
  const float* feats4 = (const float*)d_in[6];
  const float* match  = (const float*)d_in[7];
  const float* wfc    = (const float*)d_in[8];
  const float* wcls   = (const float*)d_in[9];
  (void)d_ws; (void)ws_size;  // workspace intentionally unused

  hipLaunchKernelGGL(fused_kernel, dim3(NQ / QB, NB), dim3(256), 0, stream,
                     pts, known2, feats2, known3, feats3, known4, feats4,
                     match, wfc, wcls, (float*)d_out);
}

// Round 6
// 459.022 us; speedup vs baseline: 2.3954x; 2.3954x over previous
//
#include <hip/hip_runtime.h>

typedef unsigned int       u32;
typedef unsigned long long u64;

#define NB 4
#define NQ 8192
#define QB 64            // queries per block (one per lane)
#define NP 8             // candidate parts = waves per block
#define INFKEY (0x7f800000ULL << 32)

__device__ __forceinline__ u64 umin64(u64 a, u64 b) { return a < b ? a : b; }
__device__ __forceinline__ u64 umax64(u64 a, u64 b) { return a > b ? a : b; }

// lexicographic (d, idx) insert into sorted triple; ties -> lower index
// (matches jax.lax.top_k stability)
__device__ __forceinline__ void lexins(double& e0d, double& e1d, double& e2d,
                                       int& e0i, int& e1i, int& e2i,
                                       double d, int i) {
  if (d < e2d || (d == e2d && i < e2i)) {
    if (d < e0d || (d == e0d && i < e0i)) {
      e2d = e1d; e2i = e1i; e1d = e0d; e1i = e0i; e0d = d; e0i = i;
    } else if (d < e1d || (d == e1d && i < e1i)) {
      e2d = e1d; e2i = e1i; e1d = d; e1i = i;
    } else {
      e2d = d; e2i = i;
    }
  }
}

struct Smem {
  float  qx[QB], qy[QB], qz[QB];            // f32 queries (scan)
  double qdx[QB], qdy[QB], qdz[QB], qn[QB]; // f64 queries (rescore)
  u64    dump[3][QB][NP][4];                // prefilter top-4 keys
  double mmin[QB][NP];                      // per-part mask min s
  float  wv[96];                            // folded w_cls @ w_fc
  float  part[QB][3];                       // per-level partial pred
};

// f32 prefilter scan of one part of one candidate array. Candidate loads are
// wave-uniform -> scalar (SGPR) loads; per-pair cost is 3 v_fma_f32 + 1 cmp.
// Key = (|k|^2 + 16384) - 2 p.k  >= 16384 - max|p|^2 (~2200) > 0, so the f32
// bit pattern is monotone and u64-packable with the index. Prefilter error
// ~2 ulp(16384) ~ 4e-3 m^2; top-4/part union (32 cands) then f64-rescored
// top-8 makes a true-top-3 miss need 5 consecutive d2 gaps < ~4e-3 (P~1e-10).
__device__ __forceinline__ void scan_nn(
    const float* __restrict__ src, int M, int b,
    float m2x, float m2y, float m2z, int part,
    u64& k0, u64& k1, u64& k2, u64& k3) {
  k0 = INFKEY; k1 = INFKEY; k2 = INFKEY; k3 = INFKEY;
  float thresh = __builtin_inff();
  const int L = M / NP;
  const int base = part * L;
  const float* cp = src + ((size_t)b * M + base) * 3;
  for (int j = 0; j < L; j += 8) {
    float cx[8], cy[8], cz[8];
#pragma unroll
    for (int u = 0; u < 8; ++u) {   // uniform addresses -> s_load_dwordx
      cx[u] = cp[3 * (j + u)];
      cy[u] = cp[3 * (j + u) + 1];
      cz[u] = cp[3 * (j + u) + 2];
    }
#pragma unroll
    for (int u = 0; u < 8; ++u) {
      float n2b = fmaf(cz[u], cz[u], fmaf(cy[u], cy[u], fmaf(cx[u], cx[u], 16384.0f)));
      float key = fmaf(m2x, cx[u], fmaf(m2y, cy[u], fmaf(m2z, cz[u], n2b)));
      if (key < thresh) {           // rare after warm-up
        u64 kn = ((u64)__float_as_uint(key) << 32) | (u32)(base + j + u);
        u64 t;
        t = umax64(k0, kn); k0 = umin64(k0, kn); kn = t;
        t = umax64(k1, kn); k1 = umin64(k1, kn); kn = t;
        t = umax64(k2, kn); k2 = umin64(k2, kn); kn = t;
        k3 = umin64(k3, kn);
        thresh = __uint_as_float((u32)(k3 >> 32));
      }
    }
  }
}

// f64 mask scan (threshold 0.25 is discontinuous -> full f64).
__device__ __forceinline__ double scan_mask(
    const float* __restrict__ src, int M, int b,
    double m2x, double m2y, double m2z, int part) {
  double smin = __builtin_inf();
  const int L = M / NP;
  const float* cp = src + ((size_t)b * M + part * L) * 3;
  for (int j = 0; j < L; j += 4) {
    float cx[4], cy[4], cz[4];
#pragma unroll
    for (int u = 0; u < 4; ++u) {
      cx[u] = cp[3 * (j + u)];
      cy[u] = cp[3 * (j + u) + 1];
      cz[u] = cp[3 * (j + u) + 2];
    }
#pragma unroll
    for (int u = 0; u < 4; ++u) {
      double x = (double)cx[u], y = (double)cy[u], z = (double)cz[u];
      double kn = fma(z, z, fma(y, y, x * x));     // products exact in f64
      double s = fma(m2x, x, fma(m2y, y, fma(m2z, z, kn)));
      smin = fmin(smin, s);
    }
  }
  return smin;
}

__global__ __launch_bounds__(512, 4) void fused_kernel(
    const float* __restrict__ pts,
    const float* __restrict__ k2p, const float* __restrict__ f2,
    const float* __restrict__ k3p, const float* __restrict__ f3,
    const float* __restrict__ k4p, const float* __restrict__ f4,
    const float* __restrict__ mmp,
    const float* __restrict__ wfc, const float* __restrict__ wcls,
    float* __restrict__ out) {
  __shared__ Smem s;
  const int tid = threadIdx.x;
  const int b = blockIdx.y;
  const int q0 = blockIdx.x * QB;
  const int qloc = tid & 63;
  const int part = __builtin_amdgcn_readfirstlane(tid >> 6);  // force scalar

  // phase 1: lanes of wave 0 load queries; threads 64..159 fold w_cls @ w_fc
  if (tid < QB) {
    int gq = b * NQ + q0 + tid;
    float x = pts[3 * gq], y = pts[3 * gq + 1], z = pts[3 * gq + 2];
    s.qx[tid] = x; s.qy[tid] = y; s.qz[tid] = z;
    double dx = (double)x, dy = (double)y, dz = (double)z;
    s.qdx[tid] = dx; s.qdy[tid] = dy; s.qdz[tid] = dz;
    s.qn[tid] = (dx * dx + dy * dy) + dz * dz;   // == numpy f64 grouping
  } else if (tid >= 64 && tid < 160) {
    int t = tid - 64;
    float acc = 0.f;
    for (int j = 0; j < 64; ++j) acc += wcls[j] * wfc[j * 96 + t];
    s.wv[t] = acc;
  }
  __syncthreads();

  const float fm2x = -2.0f * s.qx[qloc];
  const float fm2y = -2.0f * s.qy[qloc];
  const float fm2z = -2.0f * s.qz[qloc];
  const double dm2x = -2.0 * s.qdx[qloc];
  const double dm2y = -2.0 * s.qdy[qloc];
  const double dm2z = -2.0 * s.qdz[qloc];

  // phase 2: every wave scans its part of all 4 arrays (no syncs, no staging)
  {
    u64 k0, k1, k2, k3;
    scan_nn(k2p, 8192, b, fm2x, fm2y, fm2z, part, k0, k1, k2, k3);
    s.dump[0][qloc][part][0] = k0; s.dump[0][qloc][part][1] = k1;
    s.dump[0][qloc][part][2] = k2; s.dump[0][qloc][part][3] = k3;
    scan_nn(k3p, 4096, b, fm2x, fm2y, fm2z, part, k0, k1, k2, k3);
    s.dump[1][qloc][part][0] = k0; s.dump[1][qloc][part][1] = k1;
    s.dump[1][qloc][part][2] = k2; s.dump[1][qloc][part][3] = k3;
    scan_nn(k4p, 2048, b, fm2x, fm2y, fm2z, part, k0, k1, k2, k3);
    s.dump[2][qloc][part][0] = k0; s.dump[2][qloc][part][1] = k1;
    s.dump[2][qloc][part][2] = k2; s.dump[2][qloc][part][3] = k3;
    s.mmin[qloc][part] = scan_mask(mmp, 4096, b, dm2x, dm2y, dm2z, part);
  }
  __syncthreads();

  // phase 3: merge prefilter keys, f64 rescore (exact ref grouping), epilogue
  const int gqbase = b * NQ + q0;
  if (tid < 192) {
    const int lvl = __builtin_amdgcn_readfirstlane(tid >> 6);
    const int q = tid & 63;
    // top-8 of the 32 prefilter keys (u64 lex order = (f32 key, idx))
    u64 t8[8];
#pragma unroll
    for (int r = 0; r < 8; ++r) t8[r] = INFKEY;
    for (int p = 0; p < NP; ++p) {
#pragma unroll
      for (int r = 0; r < 4; ++r) {
        u64 kn = s.dump[lvl][q][p][r];
        if (kn < t8[7]) {
          u64 t;
#pragma unroll
          for (int m = 0; m < 7; ++m) {
            t = umax64(t8[m], kn); t8[m] = umin64(t8[m], kn); kn = t;
          }
          t8[7] = umin64(t8[7], kn);
        }
      }
    }
    // exact f64 rescore of the 8 survivors, ref-identical grouping:
    // kn=(x2+y2)+z2, dot=(qx*x+qy*y)+qz*z, d2=(qn+kn)-2*dot (products exact)
    const float* kp = (lvl == 0) ? k2p : ((lvl == 1) ? k3p : k4p);
    const int    M  = (lvl == 0) ? 8192 : ((lvl == 1) ? 4096 : 2048);
    const double qdx = s.qdx[q], qdy = s.qdy[q], qdz = s.qdz[q], qn = s.qn[q];
    double e0 = __builtin_inf(), e1 = e0, e2 = e0;
    int i0 = 0, i1 = 0, i2 = 0;
#pragma unroll
    for (int r = 0; r < 8; ++r) {
      int idx = (u32)t8[r];
      const float* c = kp + ((size_t)b * M + idx) * 3;
      double x = (double)c[0], y = (double)c[1], z = (double)c[2];
      double kn2 = (x * x + y * y) + z * z;
      double dot = (qdx * x + qdy * y) + qdz * z;
      double d2 = (qn + kn2) - 2.0 * dot;
      lexins(e0, e1, e2, i0, i1, i2, d2, idx);
    }
    double d0 = fmax(e0, 0.0), d1 = fmax(e1, 0.0), d2v = fmax(e2, 0.0);
    double r0 = 1.0 / (d0 + 1e-8);
    double r1 = 1.0 / (d1 + 1e-8);
    double r2 = 1.0 / (d2v + 1e-8);
    double sum = (r0 + r1) + r2;
    float wa = (float)(r0 / sum), wb = (float)(r1 / sum), wc = (float)(r2 / sum);

    const float* fp = (lvl == 0) ? f2 : ((lvl == 1) ? f3 : f4);
    const float* g0 = fp + ((size_t)b * M + i0) * 32;
    const float* g1 = fp + ((size_t)b * M + i1) * 32;
    const float* g2 = fp + ((size_t)b * M + i2) * 32;
    float acc = 0.f;
#pragma unroll
    for (int wd = 0; wd < 32; ++wd) {
      float v = (wa * g0[wd] + wb * g1[wd]) + wc * g2[wd];
      acc += s.wv[lvl * 32 + wd] * v;
    }
    s.part[q][lvl] = acc;
  } else if (tid < 256) {
    const int q = tid - 192;
    double sm = s.mmin[q][0];
#pragma unroll
    for (int p = 1; p < NP; ++p) sm = fmin(sm, s.mmin[q][p]);
    double dm = s.qn[q] + sm;
    // d2 < 0.25 == sqrt(max(d2,0)) < 0.5 (monotone, both strict)
    out[NB * NQ + gqbase + q] = (dm < 0.25) ? 1.0f : 0.0f;
  }
  __syncthreads();
  if (tid < QB) {
    float pred = (s.part[tid][0] + s.part[tid][1]) + s.part[tid][2];
    out[gqbase + tid] = pred;
  }
}

extern "C" void kernel_launch(void* const* d_in, const int* in_sizes, int n_in,
                              void* d_out, int out_size, void* d_ws, size_t ws_size,
                              hipStream_t stream) {
  const float* pts    = (const float*)d_in[0];
  const float* known2 = (const float*)d_in[1];
  const float* feats2 = (const float*)d_in[2];
  const float* known3 = (const float*)d_in[3];
  const float* feats3 = (const float*)d_in[4];
  const float* known4 = (const float*)d_in[5];
  const float* feats4 = (const float*)d_in[6];
  const float* match  = (const float*)d_in[7];
  const float* wfc    = (const float*)d_in[8];
  const float* wcls   = (const float*)d_in[9];
  (void)d_ws; (void)ws_size;  // workspace intentionally unused

  hipLaunchKernelGGL(fused_kernel, dim3(NQ / QB, NB), dim3(512), 0, stream,
                     pts, known2, feats2, known3, feats3, known4, feats4,
                     match, wfc, wcls, (float*)d_out);
}